// Round 5
// baseline (2181.004 us; speedup 1.0000x reference)
//
#include <hip/hip_runtime.h>
#include <hip/hip_bf16.h>
#include <stdint.h>

typedef __attribute__((ext_vector_type(8))) short bf16x8;
typedef __attribute__((ext_vector_type(4))) float f32x4;
typedef unsigned short u16;

__device__ __forceinline__ u16 f2bf(float x) {
  unsigned u = __float_as_uint(x);
  unsigned r = (u + 0x7FFFu + ((u >> 16) & 1u)) >> 16;
  return (u16)r;
}

__device__ __forceinline__ void gl_lds16(const void* g, void* l) {
  __builtin_amdgcn_global_load_lds((const __attribute__((address_space(1))) void*)g,
                                   (__attribute__((address_space(3))) void*)l, 16, 0, 0);
}

// ---------------- small setup kernels ----------------

__global__ void zero_i32_kernel(int* p, int n) {
  int i = blockIdx.x * blockDim.x + threadIdx.x;
  if (i < n) p[i] = 0;
}

__global__ void init_nbr_kernel(int* nbr, int total, int N) {
  for (int i = blockIdx.x * blockDim.x + threadIdx.x; i < total; i += gridDim.x * blockDim.x)
    nbr[i] = N;
}

__global__ void scatter_nbr_kernel(const int* __restrict__ in_idx, const int* __restrict__ out_idx,
                                   int* __restrict__ nbr, int N, int P, int NPAD) {
  const int total = 27 * P;
  for (int i = blockIdx.x * blockDim.x + threadIdx.x; i < total; i += gridDim.x * blockDim.x) {
    const int o = out_idx[i];
    if ((unsigned)o < (unsigned)N) {
      const int k = i / P;
      nbr[(size_t)k * NPAD + o] = in_idx[i];
    }
  }
}

__global__ void cvt_feats_kernel(const float* __restrict__ F, u16* __restrict__ X0, int N) {
  const int total = (N + 1) * 64;  // float4 groups of [N+1][256]
  for (int i = blockIdx.x * blockDim.x + threadIdx.x; i < total; i += gridDim.x * blockDim.x) {
    const int r = i >> 6;
    ushort4 o;
    if (r < N) {
      const float4 v = ((const float4*)F)[i];
      o.x = f2bf(v.x); o.y = f2bf(v.y); o.z = f2bf(v.z); o.w = f2bf(v.w);
    } else {
      o.x = 0; o.y = 0; o.z = 0; o.w = 0;
    }
    ((ushort4*)X0)[i] = o;
  }
}

// W: [27][CIN][512] f32  ->  Wt: [27][512][CIN] bf16 (transposed per offset)
__global__ void cvt_w_kernel(const float* __restrict__ W, u16* __restrict__ Wt, int CIN) {
  __shared__ float t[32][33];
  const int k = blockIdx.z;
  const int c0 = blockIdx.y * 32;
  const int n0 = blockIdx.x * 32;
  const int tx = threadIdx.x, ty = threadIdx.y;  // 32 x 8
  const float* Wk = W + (size_t)k * CIN * 512;
  for (int i = ty; i < 32; i += 8)
    t[i][tx] = Wk[(size_t)(c0 + i) * 512 + n0 + tx];
  __syncthreads();
  u16* Wtk = Wt + (size_t)k * 512 * CIN;
  for (int i = ty; i < 32; i += 8)
    Wtk[(size_t)(n0 + i) * CIN + c0 + tx] = f2bf(t[tx][i]);
}

// ---------------- pool member lists (2x2x2 voxel pools -> <= 8 members) ----------------

__global__ void scatter_members_kernel(const int* __restrict__ pool_idx, int* __restrict__ gcnt,
                                       int* __restrict__ mlist, int N) {
  const int r = blockIdx.x * blockDim.x + threadIdx.x;
  if (r < N) {
    const int p = pool_idx[r];
    const int pos = atomicAdd(&gcnt[p], 1);
    if (pos < 8) mlist[p * 8 + pos] = r;
  }
}

__global__ void pool_grouped_kernel(const float* __restrict__ Y, const float* __restrict__ sc,
                                    const float* __restrict__ sh, const int* __restrict__ gcnt,
                                    const int* __restrict__ mlist, float* __restrict__ out) {
  const int p = blockIdx.x;
  const int t = threadIdx.x;  // 256 threads, 2 channels each
  const int c = t * 2;
  const float s0 = sc[c], s1 = sc[c + 1];
  const float h0 = sh[c], h1 = sh[c + 1];
  int n = gcnt[p];
  if (n > 8) n = 8;
  float m0 = 0.f, m1 = 0.f;
  for (int i = 0; i < n; ++i) {
    const int r = mlist[p * 8 + i];
    const float2 v = *(const float2*)&Y[(size_t)r * 512 + c];
    m0 = fmaxf(m0, fmaxf(fmaf(v.x, s0, h0), 0.f));
    m1 = fmaxf(m1, fmaxf(fmaf(v.y, s1, h1), 0.f));
  }
  float2 o; o.x = m0; o.y = m1;
  *(float2*)&out[(size_t)p * 512 + c] = o;
}

// ---------------- conv: 256x256 tile, counted-vmcnt 4-phase/K-tile pipeline ----------------
// Y[o][n] = sum_k X[nbr[k][o]] @ Wt[k]^T.  8 waves (2M x 4N), per-wave 128x64 output.
// LDS: 4-slot ring per operand of [256 rows][32 k] bf16 half-K-tiles (kk-split).
// Slot for half H = 2t+kk is H&3. Stages for H issued >= 6 phases before use; slot
// reuse (H vs H-4) separated by the even-phase barrier. vmcnt(8) at kk boundaries.

template <int CIN>
__global__ __launch_bounds__(512, 2) void conv256_kernel(
    const u16* __restrict__ X,    // [(N+1)][CIN] bf16 (row N = zeros)
    const u16* __restrict__ Wt,   // [27][512][CIN] bf16
    const int* __restrict__ nbr,  // [27][NPAD]
    float* __restrict__ Y,        // [N][512] f32
    int N, int NPAD) {
  constexpr int KKT = CIN / 64;   // K-tiles per offset
  constexpr int NT = 27 * KKT;    // total K-tiles
  __shared__ __align__(16) u16 lds[65536];  // 128 KB: A ring 64KB + B ring 64KB
  u16* As = lds;
  u16* Bs = lds + 32768;

  const int tid = threadIdx.x;
  const int lane = tid & 63;
  const int wv = tid >> 6;        // 0..7
  const int wr = wv >> 2;         // 0..1 (M)
  const int wc = wv & 3;          // 0..3 (N)
  const int lr = lane & 15;
  const int q = lane >> 4;

  int bid = blockIdx.x;
  if ((gridDim.x & 7) == 0) {     // XCD-aware swizzle (bijective when %8==0)
    const int cpx = gridDim.x >> 3;
    bid = (bid & 7) * cpx + (bid >> 3);
  }
  const int row0 = (bid >> 1) * 256;
  const int colbase = (bid & 1) * 256;

  // staging geometry: per piece (16 KB = [256][32] half), 2 instrs (j=0,1);
  // thread covers row j*128+(tid>>2), 16B chunk (tid&3), source pre-swizzled.
  const int srow = tid >> 2;                                // 0..127
  const int csrc = (((tid & 3) ^ ((tid >> 3) & 3)) * 8);    // elems
  // ds_read offsets (elements), same XOR swizzle (chunk ^ (row>>1)&3)
  const int swz8 = (q ^ ((lr >> 1) & 3)) * 8;
  const int aoffL = (wr * 128 + lr) * 32 + swz8;
  const int boffL = (wc * 64 + lr) * 32 + swz8;

  f32x4 acc[8][4];
#pragma unroll
  for (int m = 0; m < 8; ++m)
#pragma unroll
    for (int n = 0; n < 4; ++n) acc[m][n] = (f32x4){0.f, 0.f, 0.f, 0.f};

  auto stageA = [&](int slot, int tt, int kk, int nb0, int nb1) {
    const int ko = (tt % KKT) * 64 + kk * 32;
    gl_lds16(X + (size_t)nb0 * CIN + ko + csrc, &As[slot * 8192 + wv * 512]);
    gl_lds16(X + (size_t)nb1 * CIN + ko + csrc, &As[slot * 8192 + 4096 + wv * 512]);
  };
  auto stageB = [&](int slot, int tt, int kk) {
    const int k27 = tt / KKT;
    const int ko = (tt % KKT) * 64 + kk * 32;
    const u16* base = Wt + (size_t)k27 * (512 * CIN) + ko + csrc;
    gl_lds16(base + (size_t)(colbase + srow) * CIN, &Bs[slot * 8192 + wv * 512]);
    gl_lds16(base + (size_t)(colbase + 128 + srow) * CIN, &Bs[slot * 8192 + 4096 + wv * 512]);
  };
  auto loadnbr0 = [&](int tt) {
    int t2 = (tt < NT - 1) ? tt : (NT - 1);
    const volatile int* p = nbr + (size_t)(t2 / KKT) * NPAD + row0 + srow;
    return p[0];
  };
  auto loadnbr1 = [&](int tt) {
    int t2 = (tt < NT - 1) ? tt : (NT - 1);
    const volatile int* p = nbr + (size_t)(t2 / KKT) * NPAD + row0 + 128 + srow;
    return p[0];
  };

  bf16x8 a[4], b[4];

  // prologue: pieces for halves H=0,1,2 (t=0 kk0, t=0 kk1, t=1 kk0); k27==0 for all
  int nbC0 = loadnbr0(0), nbC1 = loadnbr1(0);  // rows for k27(t+1)
  int nbN0 = nbC0, nbN1 = nbC1;                // rows for k27(t+2)
  stageA(0, 0, 0, nbC0, nbC1);
  stageB(0, 0, 0);
  stageA(1, 0, 1, nbC0, nbC1);
  stageB(1, 0, 1);
  stageA(2, 1, 0, nbC0, nbC1);
  stageB(2, 1, 0);

  for (int t = 0; t < NT; ++t) {
    const int s0 = (2 * t) & 3;
    const int s1 = (2 * t + 1) & 3;
    const u16* as0 = As + s0 * 8192;
    const u16* bs0 = Bs + s0 * 8192;
    const u16* as1 = As + s1 * 8192;
    const u16* bs1 = Bs + s1 * 8192;

    // ---- PH0 (kk0, m0-3 x n0-3) ----
    if (t < NT - 1) asm volatile("s_waitcnt vmcnt(8)" ::: "memory");
    else            asm volatile("s_waitcnt vmcnt(0)" ::: "memory");
    __builtin_amdgcn_s_barrier();
    asm volatile("" ::: "memory");
#pragma unroll
    for (int m = 0; m < 4; ++m) a[m] = *(const bf16x8*)&as0[aoffL + m * 512];
#pragma unroll
    for (int n = 0; n < 4; ++n) b[n] = *(const bf16x8*)&bs0[boffL + n * 512];
    __builtin_amdgcn_sched_barrier(0);
    if (t + 1 < NT) stageA((2 * t + 3) & 3, t + 1, 1, nbC0, nbC1);
    __builtin_amdgcn_sched_barrier(0);
    __builtin_amdgcn_s_setprio(1);
#pragma unroll
    for (int m = 0; m < 4; ++m)
#pragma unroll
      for (int n = 0; n < 4; ++n)
        acc[m][n] = __builtin_amdgcn_mfma_f32_16x16x32_bf16(a[m], b[n], acc[m][n], 0, 0, 0);
    __builtin_amdgcn_s_setprio(0);

    // ---- PH1 (kk0, m4-7 x n0-3) ----
#pragma unroll
    for (int m = 0; m < 4; ++m) a[m] = *(const bf16x8*)&as0[aoffL + (m + 4) * 512];
    __builtin_amdgcn_sched_barrier(0);
    if (t + 1 < NT) stageB((2 * t + 3) & 3, t + 1, 1);
    __builtin_amdgcn_sched_barrier(0);
    __builtin_amdgcn_s_setprio(1);
#pragma unroll
    for (int m = 0; m < 4; ++m)
#pragma unroll
      for (int n = 0; n < 4; ++n)
        acc[m + 4][n] = __builtin_amdgcn_mfma_f32_16x16x32_bf16(a[m], b[n], acc[m + 4][n], 0, 0, 0);
    __builtin_amdgcn_s_setprio(0);

    // ---- PH2 (kk1, m0-3 x n0-3) ----
    if (t < NT - 1) asm volatile("s_waitcnt vmcnt(8)" ::: "memory");
    else            asm volatile("s_waitcnt vmcnt(0)" ::: "memory");
    __builtin_amdgcn_s_barrier();
    asm volatile("" ::: "memory");
#pragma unroll
    for (int m = 0; m < 4; ++m) a[m] = *(const bf16x8*)&as1[aoffL + m * 512];
#pragma unroll
    for (int n = 0; n < 4; ++n) b[n] = *(const bf16x8*)&bs1[boffL + n * 512];
    __builtin_amdgcn_sched_barrier(0);
    if (t + 2 < NT) stageA(s0, t + 2, 0, nbN0, nbN1);  // slot (2t+4)&3 == s0
    const int nbF0 = loadnbr0(t + 3);
    const int nbF1 = loadnbr1(t + 3);
    __builtin_amdgcn_sched_barrier(0);
    __builtin_amdgcn_s_setprio(1);
#pragma unroll
    for (int m = 0; m < 4; ++m)
#pragma unroll
      for (int n = 0; n < 4; ++n)
        acc[m][n] = __builtin_amdgcn_mfma_f32_16x16x32_bf16(a[m], b[n], acc[m][n], 0, 0, 0);
    __builtin_amdgcn_s_setprio(0);

    // ---- PH3 (kk1, m4-7 x n0-3) ----
#pragma unroll
    for (int m = 0; m < 4; ++m) a[m] = *(const bf16x8*)&as1[aoffL + (m + 4) * 512];
    __builtin_amdgcn_sched_barrier(0);
    if (t + 2 < NT) stageB(s0, t + 2, 0);
    __builtin_amdgcn_sched_barrier(0);
    __builtin_amdgcn_s_setprio(1);
#pragma unroll
    for (int m = 0; m < 4; ++m)
#pragma unroll
      for (int n = 0; n < 4; ++n)
        acc[m + 4][n] = __builtin_amdgcn_mfma_f32_16x16x32_bf16(a[m], b[n], acc[m + 4][n], 0, 0, 0);
    __builtin_amdgcn_s_setprio(0);

    nbC0 = nbN0; nbC1 = nbN1;
    nbN0 = nbF0; nbN1 = nbF1;
  }

  // epilogue: C/D layout col=lane&15, row=(lane>>4)*4+reg
#pragma unroll
  for (int m = 0; m < 8; ++m) {
    const int r0 = row0 + wr * 128 + m * 16 + q * 4;
#pragma unroll
    for (int n = 0; n < 4; ++n) {
      const int c = colbase + wc * 64 + n * 16 + lr;
#pragma unroll
      for (int j = 0; j < 4; ++j) {
        const int r = r0 + j;
        if (r < N) Y[(size_t)r * 512 + c] = acc[m][n][j];
      }
    }
  }
}

// ---------------- BN ----------------

__global__ void bn_stats_kernel(const float* __restrict__ Y, float* __restrict__ st, int N) {
  const int t = threadIdx.x;  // channels 2t, 2t+1
  float s0 = 0.f, s1 = 0.f, q0 = 0.f, q1 = 0.f;
  for (int r = blockIdx.x; r < N; r += gridDim.x) {
    const float2 v = *(const float2*)&Y[(size_t)r * 512 + t * 2];
    s0 += v.x; s1 += v.y; q0 += v.x * v.x; q1 += v.y * v.y;
  }
  atomicAdd(&st[2 * t], s0);
  atomicAdd(&st[2 * t + 1], s1);
  atomicAdd(&st[512 + 2 * t], q0);
  atomicAdd(&st[512 + 2 * t + 1], q1);
}

__global__ void bn_finalize_kernel(const float* __restrict__ st, const float* __restrict__ g,
                                   const float* __restrict__ b, float* __restrict__ sc,
                                   float* __restrict__ sh, int N) {
  const int c = threadIdx.x;
  if (c < 512) {
    const float inv = 1.f / (float)N;
    const float m = st[c] * inv;
    const float v = st[512 + c] * inv - m * m;
    const float rs = rsqrtf(v + 1e-5f);
    const float s = rs * g[c];
    sc[c] = s;
    sh[c] = b[c] - m * s;
  }
}

__global__ void bn_norm_kernel(const float* __restrict__ Y, const float* __restrict__ sc,
                               const float* __restrict__ sh, u16* __restrict__ Xn, int N) {
  const int total = (N + 1) * 128;  // float4 groups of [N+1][512]
  for (int i = blockIdx.x * blockDim.x + threadIdx.x; i < total; i += gridDim.x * blockDim.x) {
    const int r = i >> 7;
    const int c = (i & 127) * 4;
    ushort4 o;
    if (r < N) {
      const float4 y = *(const float4*)&Y[(size_t)r * 512 + c];
      const float v0 = fmaxf(fmaf(y.x, sc[c + 0], sh[c + 0]), 0.f);
      const float v1 = fmaxf(fmaf(y.y, sc[c + 1], sh[c + 1]), 0.f);
      const float v2 = fmaxf(fmaf(y.z, sc[c + 2], sh[c + 2]), 0.f);
      const float v3 = fmaxf(fmaf(y.w, sc[c + 3], sh[c + 3]), 0.f);
      o.x = f2bf(v0); o.y = f2bf(v1); o.z = f2bf(v2); o.w = f2bf(v3);
    } else {
      o.x = 0; o.y = 0; o.z = 0; o.w = 0;
    }
    *(ushort4*)&Xn[(size_t)r * 512 + c] = o;
  }
}

// ---------------- host ----------------

extern "C" void kernel_launch(void* const* d_in, const int* in_sizes, int n_in,
                              void* d_out, int out_size, void* d_ws, size_t ws_size,
                              hipStream_t stream) {
  const float* feats = (const float*)d_in[0];
  const float* W1 = (const float*)d_in[1];
  const float* g1 = (const float*)d_in[2];
  const float* b1 = (const float*)d_in[3];
  const float* W2 = (const float*)d_in[4];
  const float* g2 = (const float*)d_in[5];
  const float* b2 = (const float*)d_in[6];
  const float* W3 = (const float*)d_in[7];
  const float* g3 = (const float*)d_in[8];
  const float* b3 = (const float*)d_in[9];
  const int* in_idx = (const int*)d_in[10];
  const int* out_idx = (const int*)d_in[11];
  const int* pool_idx = (const int*)d_in[12];
  float* out = (float*)d_out;

  const int N = in_sizes[0] / 256;
  const int P = in_sizes[10] / 27;
  const int NPAD = ((N + 255) / 256) * 256;  // 256-tile padding
  const int npool = out_size / 512;
  (void)n_in; (void)ws_size;

  char* w = (char*)d_ws;
  size_t off = 0;
  auto carve = [&](size_t bytes) {
    void* p = w + off;
    off += (bytes + 511) & ~(size_t)511;
    return p;
  };
  u16* X0 = (u16*)carve((size_t)(N + 1) * 256 * 2);
  u16* X1 = (u16*)carve((size_t)(N + 1) * 512 * 2);  // reused as X2 after conv2
  float* Y = (float*)carve((size_t)N * 512 * 4);
  u16* W1t = (u16*)carve((size_t)27 * 512 * 256 * 2);
  u16* W2t = (u16*)carve((size_t)27 * 512 * 512 * 2);
  u16* W3t = (u16*)carve((size_t)27 * 512 * 512 * 2);
  float* st0 = (float*)carve(1024 * 4);
  float* st1 = (float*)carve(1024 * 4);
  float* st2 = (float*)carve(1024 * 4);
  float* sc = (float*)carve(512 * 4);
  float* sh = (float*)carve(512 * 4);
  int* nbr = (int*)carve((size_t)27 * NPAD * 4);

  // pool member lists alias the X0 region (X0 dead after conv1)
  int* gcnt = (int*)X0;
  int* mlist = (int*)((char*)X0 + (1 << 17));

  const int convGrid = (NPAD / 256) * 2;  // 256x256 tiles, 2 col-tiles

  // setup
  zero_i32_kernel<<<4, 256, 0, stream>>>((int*)st0, 1024);
  zero_i32_kernel<<<4, 256, 0, stream>>>((int*)st1, 1024);
  zero_i32_kernel<<<4, 256, 0, stream>>>((int*)st2, 1024);
  init_nbr_kernel<<<2048, 256, 0, stream>>>(nbr, 27 * NPAD, N);
  scatter_nbr_kernel<<<2048, 256, 0, stream>>>(in_idx, out_idx, nbr, N, P, NPAD);
  cvt_feats_kernel<<<2048, 256, 0, stream>>>(feats, X0, N);
  cvt_w_kernel<<<dim3(16, 8, 27), dim3(32, 8), 0, stream>>>(W1, W1t, 256);
  cvt_w_kernel<<<dim3(16, 16, 27), dim3(32, 8), 0, stream>>>(W2, W2t, 512);
  cvt_w_kernel<<<dim3(16, 16, 27), dim3(32, 8), 0, stream>>>(W3, W3t, 512);

  // layer 1
  conv256_kernel<256><<<convGrid, 512, 0, stream>>>(X0, W1t, nbr, Y, N, NPAD);
  zero_i32_kernel<<<(npool + 255) / 256, 256, 0, stream>>>(gcnt, npool);
  scatter_members_kernel<<<(N + 255) / 256, 256, 0, stream>>>(pool_idx, gcnt, mlist, N);
  bn_stats_kernel<<<512, 256, 0, stream>>>(Y, st0, N);
  bn_finalize_kernel<<<1, 512, 0, stream>>>(st0, g1, b1, sc, sh, N);
  bn_norm_kernel<<<4096, 256, 0, stream>>>(Y, sc, sh, X1, N);

  // layer 2
  conv256_kernel<512><<<convGrid, 512, 0, stream>>>(X1, W2t, nbr, Y, N, NPAD);
  bn_stats_kernel<<<512, 256, 0, stream>>>(Y, st1, N);
  bn_finalize_kernel<<<1, 512, 0, stream>>>(st1, g2, b2, sc, sh, N);
  bn_norm_kernel<<<4096, 256, 0, stream>>>(Y, sc, sh, X1, N);

  // layer 3 + deterministic grouped pool (BN fused; no atomics)
  conv256_kernel<512><<<convGrid, 512, 0, stream>>>(X1, W3t, nbr, Y, N, NPAD);
  bn_stats_kernel<<<512, 256, 0, stream>>>(Y, st2, N);
  bn_finalize_kernel<<<1, 512, 0, stream>>>(st2, g3, b3, sc, sh, N);
  pool_grouped_kernel<<<npool, 256, 0, stream>>>(Y, sc, sh, gcnt, mlist, out);
}

// Round 6
// 1806.774 us; speedup vs baseline: 1.2071x; 1.2071x over previous
//
#include <hip/hip_runtime.h>
#include <hip/hip_bf16.h>
#include <stdint.h>

typedef __attribute__((ext_vector_type(8))) short bf16x8;
typedef __attribute__((ext_vector_type(4))) float f32x4;
typedef unsigned short u16;

__device__ __forceinline__ u16 f2bf(float x) {
  unsigned u = __float_as_uint(x);
  unsigned r = (u + 0x7FFFu + ((u >> 16) & 1u)) >> 16;
  return (u16)r;
}

__device__ __forceinline__ void gl_lds16(const void* g, void* l) {
  __builtin_amdgcn_global_load_lds((const __attribute__((address_space(1))) void*)g,
                                   (__attribute__((address_space(3))) void*)l, 16, 0, 0);
}

// ---------------- small setup kernels ----------------

__global__ void zero_i32_kernel(int* p, int n) {
  int i = blockIdx.x * blockDim.x + threadIdx.x;
  if (i < n) p[i] = 0;
}

__global__ void init_nbr_kernel(int* nbr, int total, int N) {
  for (int i = blockIdx.x * blockDim.x + threadIdx.x; i < total; i += gridDim.x * blockDim.x)
    nbr[i] = N;
}

__global__ void scatter_nbr_kernel(const int* __restrict__ in_idx, const int* __restrict__ out_idx,
                                   int* __restrict__ nbr, int N, int P, int NPAD) {
  const int total = 27 * P;
  for (int i = blockIdx.x * blockDim.x + threadIdx.x; i < total; i += gridDim.x * blockDim.x) {
    const int o = out_idx[i];
    if ((unsigned)o < (unsigned)N) {
      const int k = i / P;
      nbr[(size_t)k * NPAD + o] = in_idx[i];
    }
  }
}

__global__ void cvt_feats_kernel(const float* __restrict__ F, u16* __restrict__ X0, int N) {
  const int total = (N + 1) * 64;  // float4 groups of [N+1][256]
  for (int i = blockIdx.x * blockDim.x + threadIdx.x; i < total; i += gridDim.x * blockDim.x) {
    const int r = i >> 6;
    ushort4 o;
    if (r < N) {
      const float4 v = ((const float4*)F)[i];
      o.x = f2bf(v.x); o.y = f2bf(v.y); o.z = f2bf(v.z); o.w = f2bf(v.w);
    } else {
      o.x = 0; o.y = 0; o.z = 0; o.w = 0;
    }
    ((ushort4*)X0)[i] = o;
  }
}

// W: [27][CIN][512] f32  ->  Wt: [27][512][CIN] bf16 (transposed per offset)
__global__ void cvt_w_kernel(const float* __restrict__ W, u16* __restrict__ Wt, int CIN) {
  __shared__ float t[32][33];
  const int k = blockIdx.z;
  const int c0 = blockIdx.y * 32;  // CIN block
  const int n0 = blockIdx.x * 32;  // 512 block
  const int tx = threadIdx.x, ty = threadIdx.y;  // 32 x 8
  const float* Wk = W + (size_t)k * CIN * 512;
  for (int i = ty; i < 32; i += 8)
    t[i][tx] = Wk[(size_t)(c0 + i) * 512 + n0 + tx];
  __syncthreads();
  u16* Wtk = Wt + (size_t)k * 512 * CIN;
  for (int i = ty; i < 32; i += 8)
    Wtk[(size_t)(n0 + i) * CIN + c0 + tx] = f2bf(t[tx][i]);
}

// ---------------- pool member lists (2x2x2 voxel pools -> <= 8 members) ----------------

__global__ void scatter_members_kernel(const int* __restrict__ pool_idx, int* __restrict__ gcnt,
                                       int* __restrict__ mlist, int N) {
  const int r = blockIdx.x * blockDim.x + threadIdx.x;
  if (r < N) {
    const int p = pool_idx[r];
    const int pos = atomicAdd(&gcnt[p], 1);
    if (pos < 8) mlist[p * 8 + pos] = r;
  }
}

// deterministic grouped pool: one block per group; BN+ReLU applied per member, then max.
__global__ void pool_grouped_kernel(const float* __restrict__ Y, const float* __restrict__ sc,
                                    const float* __restrict__ sh, const int* __restrict__ gcnt,
                                    const int* __restrict__ mlist, float* __restrict__ out) {
  const int p = blockIdx.x;
  const int t = threadIdx.x;  // 256 threads, 2 channels each
  const int c = t * 2;
  const float s0 = sc[c], s1 = sc[c + 1];
  const float h0 = sh[c], h1 = sh[c + 1];
  int n = gcnt[p];
  if (n > 8) n = 8;
  float m0 = 0.f, m1 = 0.f;  // relu outputs are >= 0, groups non-empty
  for (int i = 0; i < n; ++i) {
    const int r = mlist[p * 8 + i];
    const float2 v = *(const float2*)&Y[(size_t)r * 512 + c];
    m0 = fmaxf(m0, fmaxf(fmaf(v.x, s0, h0), 0.f));
    m1 = fmaxf(m1, fmaxf(fmaf(v.y, s1, h1), 0.f));
  }
  float2 o; o.x = m0; o.y = m1;
  *(float2*)&out[(size_t)p * 512 + c] = o;
}

// ---------------- dense conv (R4-proven core + XCD swizzle + fused BN stats) --------------
// Y[o][n] = sum_k X[nbr[k][o]] @ Wt[k]^T. 128x128 tile, BK=32, 4 waves, 16x16x32 bf16 MFMA,
// double-buffered LDS via global_load_lds(16B), chunk-XOR swizzle (2-way banks, measured 0).
// Epilogue: writes f32 Y and accumulates per-channel sum/sumsq into st (global atomics).

template <int CIN>
__global__ __launch_bounds__(256, 2) void conv_kernel(
    const u16* __restrict__ X,    // [(N+1)][CIN] bf16 (row N = zeros)
    const u16* __restrict__ Wt,   // [27][512][CIN] bf16
    const int* __restrict__ nbr,  // [27][NPAD]
    float* __restrict__ Y,        // [N][512] f32
    float* __restrict__ st,       // [1024] f32: sums | sumsq (pre-zeroed)
    int N, int NPAD) {
  constexpr int KK = CIN / 32;
  constexpr int NSTEPS = 27 * KK;
  __shared__ __align__(16) u16 lds[16384];  // 2 bufs x (A 128x32 + B 128x32)

  const int tid = threadIdx.x;
  const int lane = tid & 63;
  const int wv = tid >> 6;
  const int wm = wv >> 1, wn = wv & 1;

  // XCD-chunked swizzle (T1): hw round-robins blockIdx across 8 XCDs; remap so
  // each XCD owns a contiguous tile range -> col-siblings of a row-tile share L2.
  int bid = blockIdx.x;
  if ((gridDim.x & 7) == 0) {
    const int cpx = gridDim.x >> 3;
    bid = (bid & 7) * cpx + (bid >> 3);
  }
  const int row0 = (bid >> 2) * 128;
  const int col0 = (bid & 3) * 128;

  const int sc = tid & 3;
  int srow[2], scs[2];
  size_t boffg[2];
#pragma unroll
  for (int i = 0; i < 2; ++i) {
    srow[i] = i * 64 + (tid >> 2);
    scs[i] = (sc ^ ((srow[i] >> 1) & 3)) * 8;
    boffg[i] = (size_t)(col0 + srow[i]) * CIN + scs[i];
  }

  const int lr = lane & 15;
  const int q = lane >> 4;
  int aoff[4], boff[4];
#pragma unroll
  for (int f = 0; f < 4; ++f) {
    const int ra = wm * 64 + f * 16 + lr;
    aoff[f] = ra * 32 + ((q ^ ((ra >> 1) & 3)) * 8);
    const int rb = wn * 64 + f * 16 + lr;
    boff[f] = 4096 + rb * 32 + ((q ^ ((rb >> 1) & 3)) * 8);
  }

  f32x4 acc[4][4];
#pragma unroll
  for (int a = 0; a < 4; ++a)
#pragma unroll
    for (int b = 0; b < 4; ++b) acc[a][b] = (f32x4){0.f, 0.f, 0.f, 0.f};

  size_t arow[2];
#pragma unroll
  for (int i = 0; i < 2; ++i) arow[i] = (size_t)nbr[row0 + srow[i]] * CIN;

#pragma unroll
  for (int i = 0; i < 2; ++i) {
    gl_lds16(X + arow[i] + scs[i], &lds[i * 2048 + wv * 512]);
    gl_lds16(Wt + boffg[i], &lds[4096 + i * 2048 + wv * 512]);
  }

  int cur = 0;
  for (int s = 0; s < NSTEPS; ++s) {
    __syncthreads();
    const int ns = s + 1;
    if (ns < NSTEPS) {
      const int k = ns / KK;
      const int kk = ns % KK;
      if (kk == 0) {
        const int* nb = nbr + (size_t)k * NPAD + row0;
#pragma unroll
        for (int i = 0; i < 2; ++i) arow[i] = (size_t)nb[srow[i]] * CIN;
      }
      const int nxt = cur ^ 1;
      const int ko = kk * 32;
      const size_t kb = (size_t)k * (512 * CIN);
#pragma unroll
      for (int i = 0; i < 2; ++i) {
        gl_lds16(X + arow[i] + ko + scs[i], &lds[nxt * 8192 + i * 2048 + wv * 512]);
        gl_lds16(Wt + kb + boffg[i] + ko, &lds[nxt * 8192 + 4096 + i * 2048 + wv * 512]);
      }
    }
    const u16* lb = &lds[cur * 8192];
    bf16x8 av[4], bv[4];
#pragma unroll
    for (int f = 0; f < 4; ++f) av[f] = *(const bf16x8*)&lb[aoff[f]];
#pragma unroll
    for (int f = 0; f < 4; ++f) bv[f] = *(const bf16x8*)&lb[boff[f]];
#pragma unroll
    for (int a = 0; a < 4; ++a)
#pragma unroll
      for (int b = 0; b < 4; ++b)
        acc[a][b] = __builtin_amdgcn_mfma_f32_16x16x32_bf16(av[a], bv[b], acc[a][b], 0, 0, 0);
    cur ^= 1;
  }

  // epilogue: C/D layout col=lane&15, row=(lane>>4)*4+reg (m89-verified)
#pragma unroll
  for (int a = 0; a < 4; ++a) {
    const int r0 = row0 + wm * 64 + a * 16 + q * 4;
#pragma unroll
    for (int b = 0; b < 4; ++b) {
      const int c = col0 + wn * 64 + b * 16 + lr;
#pragma unroll
      for (int j = 0; j < 4; ++j) {
        const int r = r0 + j;
        if (r < N) Y[(size_t)r * 512 + c] = acc[a][b][j];
      }
    }
  }

  // fused BN partial stats: per-block column sums/sumsq from the f32 acc.
  __syncthreads();                 // all waves done reading staged LDS
  float* fls = (float*)lds;        // reuse LDS: [0:128) sums, [128:256) sumsq
  if (tid < 256) fls[tid] = 0.f;
  __syncthreads();
#pragma unroll
  for (int b = 0; b < 4; ++b) {
    float s = 0.f, q2 = 0.f;
#pragma unroll
    for (int a = 0; a < 4; ++a) {
      const int rbase = row0 + wm * 64 + a * 16 + q * 4;
#pragma unroll
      for (int j = 0; j < 4; ++j) {
        if (rbase + j < N) {
          const float v = acc[a][b][j];
          s += v; q2 += v * v;
        }
      }
    }
    // reduce across the 4 q-groups (rows) within the wave
    s += __shfl_xor(s, 16);  s += __shfl_xor(s, 32);
    q2 += __shfl_xor(q2, 16); q2 += __shfl_xor(q2, 32);
    if (q == 0) {
      const int cl = wn * 64 + b * 16 + lr;  // block-local column 0..127
      atomicAdd(&fls[cl], s);
      atomicAdd(&fls[128 + cl], q2);
    }
  }
  __syncthreads();
  if (tid < 128) {
    atomicAdd(&st[col0 + tid], fls[tid]);
    atomicAdd(&st[512 + col0 + tid], fls[128 + tid]);
  }
}

// ---------------- BN ----------------

__global__ void bn_finalize_kernel(const float* __restrict__ st, const float* __restrict__ g,
                                   const float* __restrict__ b, float* __restrict__ sc,
                                   float* __restrict__ sh, int N) {
  const int c = threadIdx.x;
  if (c < 512) {
    const float inv = 1.f / (float)N;
    const float m = st[c] * inv;
    const float v = st[512 + c] * inv - m * m;
    const float rs = rsqrtf(v + 1e-5f);
    const float s = rs * g[c];
    sc[c] = s;
    sh[c] = b[c] - m * s;
  }
}

__global__ void bn_norm_kernel(const float* __restrict__ Y, const float* __restrict__ sc,
                               const float* __restrict__ sh, u16* __restrict__ Xn, int N) {
  const int total = (N + 1) * 128;  // float4 groups of [N+1][512]
  for (int i = blockIdx.x * blockDim.x + threadIdx.x; i < total; i += gridDim.x * blockDim.x) {
    const int r = i >> 7;
    const int c = (i & 127) * 4;
    ushort4 o;
    if (r < N) {
      const float4 y = *(const float4*)&Y[(size_t)r * 512 + c];
      const float v0 = fmaxf(fmaf(y.x, sc[c + 0], sh[c + 0]), 0.f);
      const float v1 = fmaxf(fmaf(y.y, sc[c + 1], sh[c + 1]), 0.f);
      const float v2 = fmaxf(fmaf(y.z, sc[c + 2], sh[c + 2]), 0.f);
      const float v3 = fmaxf(fmaf(y.w, sc[c + 3], sh[c + 3]), 0.f);
      o.x = f2bf(v0); o.y = f2bf(v1); o.z = f2bf(v2); o.w = f2bf(v3);
    } else {
      o.x = 0; o.y = 0; o.z = 0; o.w = 0;
    }
    *(ushort4*)&Xn[(size_t)r * 512 + c] = o;
  }
}

// ---------------- host ----------------

extern "C" void kernel_launch(void* const* d_in, const int* in_sizes, int n_in,
                              void* d_out, int out_size, void* d_ws, size_t ws_size,
                              hipStream_t stream) {
  const float* feats = (const float*)d_in[0];
  const float* W1 = (const float*)d_in[1];
  const float* g1 = (const float*)d_in[2];
  const float* b1 = (const float*)d_in[3];
  const float* W2 = (const float*)d_in[4];
  const float* g2 = (const float*)d_in[5];
  const float* b2 = (const float*)d_in[6];
  const float* W3 = (const float*)d_in[7];
  const float* g3 = (const float*)d_in[8];
  const float* b3 = (const float*)d_in[9];
  const int* in_idx = (const int*)d_in[10];
  const int* out_idx = (const int*)d_in[11];
  const int* pool_idx = (const int*)d_in[12];
  float* out = (float*)d_out;

  const int N = in_sizes[0] / 256;
  const int P = in_sizes[10] / 27;
  const int NPAD = ((N + 127) / 128) * 128;
  const int npool = out_size / 512;
  (void)n_in; (void)ws_size;

  // workspace carve (bytes, 512-aligned) — identical footprint to proven R1/R4 layout
  char* w = (char*)d_ws;
  size_t off = 0;
  auto carve = [&](size_t bytes) {
    void* p = w + off;
    off += (bytes + 511) & ~(size_t)511;
    return p;
  };
  u16* X0 = (u16*)carve((size_t)(N + 1) * 256 * 2);
  u16* X1 = (u16*)carve((size_t)(N + 1) * 512 * 2);  // reused as X2 after conv2
  float* Y = (float*)carve((size_t)N * 512 * 4);
  u16* W1t = (u16*)carve((size_t)27 * 512 * 256 * 2);
  u16* W2t = (u16*)carve((size_t)27 * 512 * 512 * 2);
  u16* W3t = (u16*)carve((size_t)27 * 512 * 512 * 2);
  float* st0 = (float*)carve(1024 * 4);
  float* st1 = (float*)carve(1024 * 4);
  float* st2 = (float*)carve(1024 * 4);
  float* sc = (float*)carve(512 * 4);
  float* sh = (float*)carve(512 * 4);
  int* nbr = (int*)carve((size_t)27 * NPAD * 4);

  // pool member lists alias the X0 region (X0 dead after conv1; lists built after
  // conv1 launches, consumed only by the final pool kernel).
  int* gcnt = (int*)X0;                        // npool ints
  int* mlist = (int*)((char*)X0 + (1 << 17));  // npool*8 ints

  const int convGrid = (NPAD / 128) * 4;  // 1568 for N=50000 (divisible by 8)

  // setup
  zero_i32_kernel<<<4, 256, 0, stream>>>((int*)st0, 1024);
  zero_i32_kernel<<<4, 256, 0, stream>>>((int*)st1, 1024);
  zero_i32_kernel<<<4, 256, 0, stream>>>((int*)st2, 1024);
  init_nbr_kernel<<<2048, 256, 0, stream>>>(nbr, 27 * NPAD, N);
  scatter_nbr_kernel<<<2048, 256, 0, stream>>>(in_idx, out_idx, nbr, N, P, NPAD);
  cvt_feats_kernel<<<2048, 256, 0, stream>>>(feats, X0, N);
  cvt_w_kernel<<<dim3(16, 8, 27), dim3(32, 8), 0, stream>>>(W1, W1t, 256);
  cvt_w_kernel<<<dim3(16, 16, 27), dim3(32, 8), 0, stream>>>(W2, W2t, 512);
  cvt_w_kernel<<<dim3(16, 16, 27), dim3(32, 8), 0, stream>>>(W3, W3t, 512);

  // layer 1 (stats fused into conv epilogue)
  conv_kernel<256><<<convGrid, 256, 0, stream>>>(X0, W1t, nbr, Y, st0, N, NPAD);
  // X0 dead from here -> build pool member lists in its space
  zero_i32_kernel<<<(npool + 255) / 256, 256, 0, stream>>>(gcnt, npool);
  scatter_members_kernel<<<(N + 255) / 256, 256, 0, stream>>>(pool_idx, gcnt, mlist, N);
  bn_finalize_kernel<<<1, 512, 0, stream>>>(st0, g1, b1, sc, sh, N);
  bn_norm_kernel<<<4096, 256, 0, stream>>>(Y, sc, sh, X1, N);

  // layer 2
  conv_kernel<512><<<convGrid, 256, 0, stream>>>(X1, W2t, nbr, Y, st1, N, NPAD);
  bn_finalize_kernel<<<1, 512, 0, stream>>>(st1, g2, b2, sc, sh, N);
  bn_norm_kernel<<<4096, 256, 0, stream>>>(Y, sc, sh, X1, N);  // X2 aliases X1

  // layer 3 + deterministic grouped pool (BN fused; no atomics on output)
  conv_kernel<512><<<convGrid, 256, 0, stream>>>(X1, W3t, nbr, Y, st2, N, NPAD);
  bn_finalize_kernel<<<1, 512, 0, stream>>>(st2, g3, b3, sc, sh, N);
  pool_grouped_kernel<<<npool, 256, 0, stream>>>(Y, sc, sh, gcnt, mlist, out);
}

// Round 8
// 1777.601 us; speedup vs baseline: 1.2269x; 1.0164x over previous
//
#include <hip/hip_runtime.h>
#include <hip/hip_bf16.h>
#include <stdint.h>

typedef __attribute__((ext_vector_type(8))) short bf16x8;
typedef __attribute__((ext_vector_type(4))) float f32x4;
typedef unsigned short u16;

__device__ __forceinline__ u16 f2bf(float x) {
  unsigned u = __float_as_uint(x);
  unsigned r = (u + 0x7FFFu + ((u >> 16) & 1u)) >> 16;
  return (u16)r;
}

__device__ __forceinline__ void gl_lds16(const void* g, void* l) {
  __builtin_amdgcn_global_load_lds((const __attribute__((address_space(1))) void*)g,
                                   (__attribute__((address_space(3))) void*)l, 16, 0, 0);
}

// ---------------- small setup kernels ----------------

__global__ void zero_i32_kernel(int* p, int n) {
  int i = blockIdx.x * blockDim.x + threadIdx.x;
  if (i < n) p[i] = 0;
}

__global__ void init_nbr_kernel(int* nbr, int total, int N) {
  for (int i = blockIdx.x * blockDim.x + threadIdx.x; i < total; i += gridDim.x * blockDim.x)
    nbr[i] = N;
}

__global__ void scatter_nbr_kernel(const int* __restrict__ in_idx, const int* __restrict__ out_idx,
                                   int* __restrict__ nbr, int N, int P, int NPAD) {
  const int total = 27 * P;
  for (int i = blockIdx.x * blockDim.x + threadIdx.x; i < total; i += gridDim.x * blockDim.x) {
    const int o = out_idx[i];
    if ((unsigned)o < (unsigned)N) {
      const int k = i / P;
      nbr[(size_t)k * NPAD + o] = in_idx[i];
    }
  }
}

__global__ void cvt_feats_kernel(const float* __restrict__ F, u16* __restrict__ X0, int N) {
  const int total = (N + 1) * 64;  // float4 groups of [N+1][256]
  for (int i = blockIdx.x * blockDim.x + threadIdx.x; i < total; i += gridDim.x * blockDim.x) {
    const int r = i >> 6;
    ushort4 o;
    if (r < N) {
      const float4 v = ((const float4*)F)[i];
      o.x = f2bf(v.x); o.y = f2bf(v.y); o.z = f2bf(v.z); o.w = f2bf(v.w);
    } else {
      o.x = 0; o.y = 0; o.z = 0; o.w = 0;
    }
    ((ushort4*)X0)[i] = o;
  }
}

// W: [27][CIN][512] f32  ->  Wt: [27][512][CIN] bf16 (transposed per offset)
__global__ void cvt_w_kernel(const float* __restrict__ W, u16* __restrict__ Wt, int CIN) {
  __shared__ float t[32][33];
  const int k = blockIdx.z;
  const int c0 = blockIdx.y * 32;
  const int n0 = blockIdx.x * 32;
  const int tx = threadIdx.x, ty = threadIdx.y;  // 32 x 8
  const float* Wk = W + (size_t)k * CIN * 512;
  for (int i = ty; i < 32; i += 8)
    t[i][tx] = Wk[(size_t)(c0 + i) * 512 + n0 + tx];
  __syncthreads();
  u16* Wtk = Wt + (size_t)k * 512 * CIN;
  for (int i = ty; i < 32; i += 8)
    Wtk[(size_t)(n0 + i) * CIN + c0 + tx] = f2bf(t[tx][i]);
}

// ---------------- pool member lists (2x2x2 voxel pools -> <= 8 members) ----------------

__global__ void scatter_members_kernel(const int* __restrict__ pool_idx, int* __restrict__ gcnt,
                                       int* __restrict__ mlist, int N) {
  const int r = blockIdx.x * blockDim.x + threadIdx.x;
  if (r < N) {
    const int p = pool_idx[r];
    const int pos = atomicAdd(&gcnt[p], 1);
    if (pos < 8) mlist[p * 8 + pos] = r;
  }
}

__global__ void pool_grouped_kernel(const float* __restrict__ Y, const float* __restrict__ sc,
                                    const float* __restrict__ sh, const int* __restrict__ gcnt,
                                    const int* __restrict__ mlist, float* __restrict__ out) {
  const int p = blockIdx.x;
  const int t = threadIdx.x;  // 256 threads, 2 channels each
  const int c = t * 2;
  const float s0 = sc[c], s1 = sc[c + 1];
  const float h0 = sh[c], h1 = sh[c + 1];
  int n = gcnt[p];
  if (n > 8) n = 8;
  float m0 = 0.f, m1 = 0.f;
  for (int i = 0; i < n; ++i) {
    const int r = mlist[p * 8 + i];
    const float2 v = *(const float2*)&Y[(size_t)r * 512 + c];
    m0 = fmaxf(m0, fmaxf(fmaf(v.x, s0, h0), 0.f));
    m1 = fmaxf(m1, fmaxf(fmaf(v.y, s1, h1), 0.f));
  }
  float2 o; o.x = m0; o.y = m1;
  *(float2*)&out[(size_t)p * 512 + c] = o;
}

// ---------------- dense conv: 128x128 tile + counted-vmcnt 3-slot ring --------------
// Y[o][n] = sum_k X[nbr[k][o]] @ Wt[k]^T. BK=32, 4 waves, 16x16x32 bf16 MFMA.
// Outer loop = 27 segments, inner loop = KK steps fully unrolled (static kk).
// 3 LDS slots of (A 8KB | B 8KB); stages for t+1,t+2 in flight across raw s_barrier;
// per-step asm vmcnt(4) (vmcnt(6) at kk==3 to skip the 2 nbr loads; vmcnt(0) only
// at the final step). nbr indices: plain compiler-tracked loads issued at kk==2,
// consumed at kk==KK-2 (compiler inserts its own counted wait - no asm loads).
// Epilogue: writes f32 Y and accumulates per-channel sum/sumsq into st.

template <int CIN>
__global__ __launch_bounds__(256, 2) void conv_kernel(
    const u16* __restrict__ X,    // [(N+1)][CIN] bf16 (row N = zeros)
    const u16* __restrict__ Wt,   // [27][512][CIN] bf16
    const int* __restrict__ nbr,  // [27][NPAD]
    float* __restrict__ Y,        // [N][512] f32
    float* __restrict__ st,       // [1024] f32: sums | sumsq (pre-zeroed)
    int N, int NPAD) {
  constexpr int KK = CIN / 32;  // K-steps per offset (8 or 16)
  __shared__ __align__(16) u16 lds[24576];  // 3 slots x 8192 u16 (48 KB)

  const int tid = threadIdx.x;
  const int lane = tid & 63;
  const int wv = tid >> 6;
  const int wm = wv >> 1, wn = wv & 1;

  int bid = blockIdx.x;
  if ((gridDim.x & 7) == 0) {  // XCD-chunked swizzle (free)
    const int cpx = gridDim.x >> 3;
    bid = (bid & 7) * cpx + (bid >> 3);
  }
  const int row0 = (bid >> 2) * 128;
  const int col0 = (bid & 3) * 128;

  // staging geometry: covers rows (i*64 + tid>>2), 16B chunk tid&3, pre-swizzled src
  const int srow = tid >> 2;  // 0..63
  const int scs = (((tid & 3) ^ ((srow >> 1) & 3)) * 8);
  const size_t boffg0 = (size_t)(col0 + srow) * CIN + scs;
  const size_t boffg1 = (size_t)(col0 + 64 + srow) * CIN + scs;

  // ds_read fragment offsets (elements), same XOR swizzle
  const int lr = lane & 15;
  const int q = lane >> 4;
  int aoff[4], boff[4];
#pragma unroll
  for (int f = 0; f < 4; ++f) {
    const int ra = wm * 64 + f * 16 + lr;
    aoff[f] = ra * 32 + ((q ^ ((ra >> 1) & 3)) * 8);
    const int rb = wn * 64 + f * 16 + lr;
    boff[f] = 4096 + rb * 32 + ((q ^ ((rb >> 1) & 3)) * 8);
  }

  f32x4 acc[4][4];
#pragma unroll
  for (int a = 0; a < 4; ++a)
#pragma unroll
    for (int b = 0; b < 4; ++b) acc[a][b] = (f32x4){0.f, 0.f, 0.f, 0.f};

  auto stage = [&](int slot, size_t a0, size_t a1, int ko, size_t kb) {
    u16* sb = &lds[slot * 8192];
    gl_lds16(X + a0 + ko + scs, &sb[wv * 512]);
    gl_lds16(X + a1 + ko + scs, &sb[2048 + wv * 512]);
    gl_lds16(Wt + kb + boffg0 + ko, &sb[4096 + wv * 512]);
    gl_lds16(Wt + kb + boffg1 + ko, &sb[6144 + wv * 512]);
  };

  // prologue: segment-0 row indices (plain loads), stage steps 0 and 1
  size_t arow0 = (size_t)nbr[row0 + srow] * CIN;
  size_t arow1 = (size_t)nbr[row0 + 64 + srow] * CIN;
  stage(0, arow0, arow1, 0, 0);
  stage(1, arow0, arow1, 32, 0);

  int sl = 0, sl2 = 2;  // slot of t, slot of t+2 (mod 3)
  int nn0 = 0, nn1 = 0;

  // helper macro for one pipeline step body (static kk within unrolled loops)
#define STEP_BODY(WAITN, DO_NBR, DO_STAGE, A0, A1, KO, KB)                        \
  {                                                                               \
    asm volatile("s_waitcnt vmcnt(" #WAITN ")" ::: "memory");                     \
    __builtin_amdgcn_s_barrier();                                                 \
    asm volatile("" ::: "memory");                                                \
    const u16* lb = &lds[sl * 8192];                                              \
    bf16x8 av[4], bv[4];                                                          \
    _Pragma("unroll") for (int f = 0; f < 4; ++f) av[f] = *(const bf16x8*)&lb[aoff[f]]; \
    _Pragma("unroll") for (int f = 0; f < 4; ++f) bv[f] = *(const bf16x8*)&lb[boff[f]]; \
    __builtin_amdgcn_sched_barrier(0);                                            \
    if (DO_NBR) {                                                                 \
      nn0 = nbr[(size_t)(s + 1) * NPAD + row0 + srow];                            \
      nn1 = nbr[(size_t)(s + 1) * NPAD + row0 + 64 + srow];                       \
    }                                                                             \
    if (DO_STAGE) stage(sl2, (A0), (A1), (KO), (KB));                             \
    __builtin_amdgcn_sched_barrier(0);                                            \
    __builtin_amdgcn_s_setprio(1);                                                \
    _Pragma("unroll") for (int a = 0; a < 4; ++a)                                 \
      _Pragma("unroll") for (int b = 0; b < 4; ++b)                               \
        acc[a][b] = __builtin_amdgcn_mfma_f32_16x16x32_bf16(av[a], bv[b], acc[a][b], 0, 0, 0); \
    __builtin_amdgcn_s_setprio(0);                                                \
    sl = (sl == 2) ? 0 : sl + 1;                                                  \
    sl2 = (sl2 == 2) ? 0 : sl2 + 1;                                               \
  }

  // main segments 0..25
  for (int s = 0; s < 26; ++s) {
    const size_t kbC = (size_t)s * (512 * CIN);
    const size_t kbN = (size_t)(s + 1) * (512 * CIN);
#pragma unroll
    for (int kk = 0; kk < KK; ++kk) {
      const bool donbr = (kk == 2);
      if (kk < KK - 2) {
        if (kk == 3) STEP_BODY(6, donbr, true, arow0, arow1, (kk + 2) * 32, kbC)
        else         STEP_BODY(4, donbr, true, arow0, arow1, (kk + 2) * 32, kbC)
      } else {
        // stage crosses into segment s+1 (uses nn loaded at kk==2)
        STEP_BODY(4, false, true, (size_t)nn0 * CIN, (size_t)nn1 * CIN,
                  (kk + 2 - KK) * 32, kbN)
      }
    }
    arow0 = (size_t)nn0 * CIN;
    arow1 = (size_t)nn1 * CIN;
  }
  // epilogue segment s=26: no nbr prefetch; last 2 steps stage nothing
  {
    const int s = 26;
    const size_t kbC = (size_t)s * (512 * CIN);
    (void)s;
#pragma unroll
    for (int kk = 0; kk < KK; ++kk) {
      if (kk < KK - 2)      STEP_BODY(4, false, true, arow0, arow1, (kk + 2) * 32, kbC)
      else if (kk < KK - 1) STEP_BODY(4, false, false, arow0, arow1, 0, kbC)
      else                  STEP_BODY(0, false, false, arow0, arow1, 0, kbC)
    }
  }
#undef STEP_BODY

  // epilogue: C/D layout col=lane&15, row=(lane>>4)*4+reg (m89-verified)
#pragma unroll
  for (int a = 0; a < 4; ++a) {
    const int r0 = row0 + wm * 64 + a * 16 + q * 4;
#pragma unroll
    for (int b = 0; b < 4; ++b) {
      const int c = col0 + wn * 64 + b * 16 + lr;
#pragma unroll
      for (int j = 0; j < 4; ++j) {
        const int r = r0 + j;
        if (r < N) Y[(size_t)r * 512 + c] = acc[a][b][j];
      }
    }
  }

  // fused BN partial stats from the f32 acc
  __syncthreads();
  float* fls = (float*)lds;
  if (tid < 256) fls[tid] = 0.f;
  __syncthreads();
#pragma unroll
  for (int b = 0; b < 4; ++b) {
    float s = 0.f, q2 = 0.f;
#pragma unroll
    for (int a = 0; a < 4; ++a) {
      const int rbase = row0 + wm * 64 + a * 16 + q * 4;
#pragma unroll
      for (int j = 0; j < 4; ++j) {
        if (rbase + j < N) {
          const float v = acc[a][b][j];
          s += v; q2 += v * v;
        }
      }
    }
    s += __shfl_xor(s, 16);  s += __shfl_xor(s, 32);
    q2 += __shfl_xor(q2, 16); q2 += __shfl_xor(q2, 32);
    if (q == 0) {
      const int cl = wn * 64 + b * 16 + lr;
      atomicAdd(&fls[cl], s);
      atomicAdd(&fls[128 + cl], q2);
    }
  }
  __syncthreads();
  if (tid < 128) {
    atomicAdd(&st[col0 + tid], fls[tid]);
    atomicAdd(&st[512 + col0 + tid], fls[128 + tid]);
  }
}

// ---------------- BN ----------------

__global__ void bn_finalize_kernel(const float* __restrict__ st, const float* __restrict__ g,
                                   const float* __restrict__ b, float* __restrict__ sc,
                                   float* __restrict__ sh, int N) {
  const int c = threadIdx.x;
  if (c < 512) {
    const float inv = 1.f / (float)N;
    const float m = st[c] * inv;
    const float v = st[512 + c] * inv - m * m;
    const float rs = rsqrtf(v + 1e-5f);
    const float s = rs * g[c];
    sc[c] = s;
    sh[c] = b[c] - m * s;
  }
}

__global__ void bn_norm_kernel(const float* __restrict__ Y, const float* __restrict__ sc,
                               const float* __restrict__ sh, u16* __restrict__ Xn, int N) {
  const int total = (N + 1) * 128;  // float4 groups of [N+1][512]
  for (int i = blockIdx.x * blockDim.x + threadIdx.x; i < total; i += gridDim.x * blockDim.x) {
    const int r = i >> 7;
    const int c = (i & 127) * 4;
    ushort4 o;
    if (r < N) {
      const float4 y = *(const float4*)&Y[(size_t)r * 512 + c];
      const float v0 = fmaxf(fmaf(y.x, sc[c + 0], sh[c + 0]), 0.f);
      const float v1 = fmaxf(fmaf(y.y, sc[c + 1], sh[c + 1]), 0.f);
      const float v2 = fmaxf(fmaf(y.z, sc[c + 2], sh[c + 2]), 0.f);
      const float v3 = fmaxf(fmaf(y.w, sc[c + 3], sh[c + 3]), 0.f);
      o.x = f2bf(v0); o.y = f2bf(v1); o.z = f2bf(v2); o.w = f2bf(v3);
    } else {
      o.x = 0; o.y = 0; o.z = 0; o.w = 0;
    }
    *(ushort4*)&Xn[(size_t)r * 512 + c] = o;
  }
}

// ---------------- host ----------------

extern "C" void kernel_launch(void* const* d_in, const int* in_sizes, int n_in,
                              void* d_out, int out_size, void* d_ws, size_t ws_size,
                              hipStream_t stream) {
  const float* feats = (const float*)d_in[0];
  const float* W1 = (const float*)d_in[1];
  const float* g1 = (const float*)d_in[2];
  const float* b1 = (const float*)d_in[3];
  const float* W2 = (const float*)d_in[4];
  const float* g2 = (const float*)d_in[5];
  const float* b2 = (const float*)d_in[6];
  const float* W3 = (const float*)d_in[7];
  const float* g3 = (const float*)d_in[8];
  const float* b3 = (const float*)d_in[9];
  const int* in_idx = (const int*)d_in[10];
  const int* out_idx = (const int*)d_in[11];
  const int* pool_idx = (const int*)d_in[12];
  float* out = (float*)d_out;

  const int N = in_sizes[0] / 256;
  const int P = in_sizes[10] / 27;
  const int NPAD = ((N + 127) / 128) * 128;
  const int npool = out_size / 512;
  (void)n_in; (void)ws_size;

  char* w = (char*)d_ws;
  size_t off = 0;
  auto carve = [&](size_t bytes) {
    void* p = w + off;
    off += (bytes + 511) & ~(size_t)511;
    return p;
  };
  u16* X0 = (u16*)carve((size_t)(N + 1) * 256 * 2);
  u16* X1 = (u16*)carve((size_t)(N + 1) * 512 * 2);  // reused as X2 after conv2
  float* Y = (float*)carve((size_t)N * 512 * 4);
  u16* W1t = (u16*)carve((size_t)27 * 512 * 256 * 2);
  u16* W2t = (u16*)carve((size_t)27 * 512 * 512 * 2);
  u16* W3t = (u16*)carve((size_t)27 * 512 * 512 * 2);
  float* st0 = (float*)carve(1024 * 4);
  float* st1 = (float*)carve(1024 * 4);
  float* st2 = (float*)carve(1024 * 4);
  float* sc = (float*)carve(512 * 4);
  float* sh = (float*)carve(512 * 4);
  int* nbr = (int*)carve((size_t)27 * NPAD * 4);

  // pool member lists alias the X0 region (X0 dead after conv1)
  int* gcnt = (int*)X0;
  int* mlist = (int*)((char*)X0 + (1 << 17));

  const int convGrid = (NPAD / 128) * 4;  // 1568 for N=50000 (divisible by 8)

  // setup
  zero_i32_kernel<<<4, 256, 0, stream>>>((int*)st0, 1024);
  zero_i32_kernel<<<4, 256, 0, stream>>>((int*)st1, 1024);
  zero_i32_kernel<<<4, 256, 0, stream>>>((int*)st2, 1024);
  init_nbr_kernel<<<2048, 256, 0, stream>>>(nbr, 27 * NPAD, N);
  scatter_nbr_kernel<<<2048, 256, 0, stream>>>(in_idx, out_idx, nbr, N, P, NPAD);
  cvt_feats_kernel<<<2048, 256, 0, stream>>>(feats, X0, N);
  cvt_w_kernel<<<dim3(16, 8, 27), dim3(32, 8), 0, stream>>>(W1, W1t, 256);
  cvt_w_kernel<<<dim3(16, 16, 27), dim3(32, 8), 0, stream>>>(W2, W2t, 512);
  cvt_w_kernel<<<dim3(16, 16, 27), dim3(32, 8), 0, stream>>>(W3, W3t, 512);

  // layer 1 (stats fused into conv epilogue)
  conv_kernel<256><<<convGrid, 256, 0, stream>>>(X0, W1t, nbr, Y, st0, N, NPAD);
  // X0 dead from here -> build pool member lists in its space
  zero_i32_kernel<<<(npool + 255) / 256, 256, 0, stream>>>(gcnt, npool);
  scatter_members_kernel<<<(N + 255) / 256, 256, 0, stream>>>(pool_idx, gcnt, mlist, N);
  bn_finalize_kernel<<<1, 512, 0, stream>>>(st0, g1, b1, sc, sh, N);
  bn_norm_kernel<<<4096, 256, 0, stream>>>(Y, sc, sh, X1, N);

  // layer 2
  conv_kernel<512><<<convGrid, 256, 0, stream>>>(X1, W2t, nbr, Y, st1, N, NPAD);
  bn_finalize_kernel<<<1, 512, 0, stream>>>(st1, g2, b2, sc, sh, N);
  bn_norm_kernel<<<4096, 256, 0, stream>>>(Y, sc, sh, X1, N);  // X2 aliases X1

  // layer 3 + deterministic grouped pool
  conv_kernel<512><<<convGrid, 256, 0, stream>>>(X1, W3t, nbr, Y, st2, N, NPAD);
  bn_finalize_kernel<<<1, 512, 0, stream>>>(st2, g3, b3, sc, sh, N);
  pool_grouped_kernel<<<npool, 256, 0, stream>>>(Y, sc, sh, gcnt, mlist, out);
}